// Round 1
// baseline (1083.427 us; speedup 1.0000x reference)
//
#include <hip/hip_runtime.h>
#include <cstdint>
#include <cstddef>

// DiffTransformerBlock on gfx950 — bf16 MFMA implementation, fp32 accum.
// B=2,S=1024,E=2048,H=16,D=128,HID=4096. All GEMMs via mfma_f32_16x16x32_bf16
// with 128x128 tiles (m97 structure), weights pre-transposed to [N][K] bf16.

#define DEV __device__ __forceinline__

typedef short bf16x8 __attribute__((ext_vector_type(8)));   // 8 bf16 = 4 VGPR (guide §3)
typedef float f32x4 __attribute__((ext_vector_type(4)));
typedef unsigned short u16x4 __attribute__((ext_vector_type(4)));

DEV unsigned short f2bf(float f) {
    unsigned u = __float_as_uint(f);
    u += 0x7fffu + ((u >> 16) & 1u);   // round-to-nearest-even
    return (unsigned short)(u >> 16);
}
DEV float bf2f(unsigned short h) { return __uint_as_float(((unsigned)h) << 16); }

DEV void gload16(const void* g, void* l) {
    __builtin_amdgcn_global_load_lds((const __attribute__((address_space(1))) void*)g,
                                     (__attribute__((address_space(3))) void*)l, 16, 0, 0);
}

DEV f32x4 mfma16(bf16x8 a, bf16x8 b, f32x4 c) {
    return __builtin_amdgcn_mfma_f32_16x16x32_bf16(a, b, c, 0, 0, 0);
}

// ---------------- transpose + cast fp32 [K][N] -> bf16 [N][K] ----------------
__global__ __launch_bounds__(256) void k_transpose_cast(const float* __restrict__ src,
                                                        unsigned short* __restrict__ dst,
                                                        int K, int N) {
    __shared__ float tile[64][65];
    int nb = blockIdx.x * 64, kb = blockIdx.y * 64;
    int t = threadIdx.x;
    int r0 = t >> 4, c4 = (t & 15) * 4;
#pragma unroll
    for (int p = 0; p < 4; p++) {
        int r = p * 16 + r0;
        f32x4 v = *(const f32x4*)(src + (size_t)(kb + r) * N + nb + c4);
        tile[r][c4 + 0] = v[0]; tile[r][c4 + 1] = v[1];
        tile[r][c4 + 2] = v[2]; tile[r][c4 + 3] = v[3];
    }
    __syncthreads();
#pragma unroll
    for (int p = 0; p < 4; p++) {
        int n = p * 16 + r0;
        u16x4 o;
#pragma unroll
        for (int i = 0; i < 4; i++) o[i] = f2bf(tile[c4 + i][n]);
        *(u16x4*)(dst + (size_t)(nb + n) * K + kb + c4) = o;
    }
}

// ---------------- cast fp32 -> bf16 (8 elems/thread) ----------------
__global__ __launch_bounds__(256) void k_cast_bf16(const float* __restrict__ src,
                                                   unsigned short* __restrict__ dst, int n8) {
    int idx = blockIdx.x * 256 + threadIdx.x;
    if (idx >= n8) return;
    f32x4 a = ((const f32x4*)src)[idx * 2];
    f32x4 b = ((const f32x4*)src)[idx * 2 + 1];
    u16x4 oa, ob;
#pragma unroll
    for (int i = 0; i < 4; i++) { oa[i] = f2bf(a[i]); ob[i] = f2bf(b[i]); }
    ((u16x4*)dst)[idx * 2] = oa;
    ((u16x4*)dst)[idx * 2 + 1] = ob;
}

// ---------------- lambda scalar ----------------
__global__ void k_lam(const float* lq1, const float* lk1, const float* lq2,
                      const float* lk2, float* out) {
    int t = threadIdx.x;  // 128 threads
    float a = lq1[t] * lk1[t];
    float b = lq2[t] * lk2[t];
#pragma unroll
    for (int off = 32; off; off >>= 1) { a += __shfl_xor(a, off); b += __shfl_xor(b, off); }
    __shared__ float sa[2], sb[2];
    if ((t & 63) == 0) { sa[t >> 6] = a; sb[t >> 6] = b; }
    __syncthreads();
    if (t == 0) out[0] = __expf(sa[0] + sa[1]) - __expf(sb[0] + sb[1]) + 0.8f;
}

// ---------------- GEMM: C[M,N] = A[M,K](bf16) @ Bt[N,K](bf16)^T ----------------
// MODE 0: write bf16 C. MODE 1: write fp32 (C + addend). MODE 2: write fp32 C.
template <int MODE>
__global__ __launch_bounds__(256) void k_gemm(const unsigned short* __restrict__ A,
                                              const unsigned short* __restrict__ Bt,
                                              void* __restrict__ Cout,
                                              const float* __restrict__ addend,
                                              int M, int N, int K) {
    __shared__ unsigned short As[128 * 64];
    __shared__ unsigned short Bs[128 * 64];
    int t = threadIdx.x;
    int lane = t & 63, wave = t >> 6;
    int wr = wave >> 1, wc = wave & 1;
    int li = lane & 15, lg = lane >> 4;
    int bm = blockIdx.x, bn = blockIdx.y;
    f32x4 acc[4][4];
#pragma unroll
    for (int m = 0; m < 4; m++)
#pragma unroll
        for (int n = 0; n < 4; n++)
#pragma unroll
            for (int r = 0; r < 4; r++) acc[m][n][r] = 0.f;

    int sr = t >> 3, sc = (t & 7) * 8;
    const unsigned short* Ag = A + (size_t)(bm * 128 + sr) * K + sc;
    const unsigned short* Bg = Bt + (size_t)(bn * 128 + sr) * K + sc;
    int nk = K >> 6;
    for (int kt = 0; kt < nk; kt++) {
#pragma unroll
        for (int i = 0; i < 4; i++) {
            gload16(Ag + (size_t)i * 32 * K + kt * 64, As + (i * 256 + t) * 8);
            gload16(Bg + (size_t)i * 32 * K + kt * 64, Bs + (i * 256 + t) * 8);
        }
        __syncthreads();
#pragma unroll
        for (int ks = 0; ks < 2; ks++) {
            bf16x8 af[4], bfr[4];
#pragma unroll
            for (int m = 0; m < 4; m++)
                af[m] = *(const bf16x8*)(As + (wr * 64 + m * 16 + li) * 64 + ks * 32 + lg * 8);
#pragma unroll
            for (int n = 0; n < 4; n++)
                bfr[n] = *(const bf16x8*)(Bs + (wc * 64 + n * 16 + li) * 64 + ks * 32 + lg * 8);
#pragma unroll
            for (int m = 0; m < 4; m++)
#pragma unroll
                for (int n = 0; n < 4; n++)
                    acc[m][n] = mfma16(af[m], bfr[n], acc[m][n]);
        }
        __syncthreads();
    }
    int row0 = bm * 128 + wr * 64, col0 = bn * 128 + wc * 64;
#pragma unroll
    for (int m = 0; m < 4; m++) {
#pragma unroll
        for (int n = 0; n < 4; n++) {
            int col = col0 + n * 16 + li;
#pragma unroll
            for (int r = 0; r < 4; r++) {
                int row = row0 + m * 16 + lg * 4 + r;
                float v = acc[m][n][r];
                if constexpr (MODE == 0)
                    ((unsigned short*)Cout)[(size_t)row * N + col] = f2bf(v);
                else if constexpr (MODE == 1)
                    ((float*)Cout)[(size_t)row * N + col] = v + addend[(size_t)row * N + col];
                else
                    ((float*)Cout)[(size_t)row * N + col] = v;
            }
        }
    }
}

// ---------------- V transpose: QKV[.,8192+h*256+n] -> Vt[bh][n][t] ----------------
__global__ __launch_bounds__(256) void k_vtrans(const unsigned short* __restrict__ QKV,
                                                unsigned short* __restrict__ Vt) {
    __shared__ unsigned short vtile[64][65];
    int t0 = blockIdx.x * 64, n0 = blockIdx.y * 64, bh = blockIdx.z;
    int b = bh >> 4, h = bh & 15;
    int t = threadIdx.x;
    int r0 = t >> 4, c4 = (t & 15) * 4;
    const unsigned short* src = QKV + (size_t)(b * 1024 + t0) * 12288 + 8192 + h * 256 + n0;
#pragma unroll
    for (int p = 0; p < 4; p++) {
        int r = p * 16 + r0;
        u16x4 v = *(const u16x4*)(src + (size_t)r * 12288 + c4);
        vtile[r][c4 + 0] = v[0]; vtile[r][c4 + 1] = v[1];
        vtile[r][c4 + 2] = v[2]; vtile[r][c4 + 3] = v[3];
    }
    __syncthreads();
    unsigned short* dst = Vt + ((size_t)bh * 256 + n0) * 1024 + t0;
#pragma unroll
    for (int p = 0; p < 4; p++) {
        int n = p * 16 + r0;
        u16x4 o;
#pragma unroll
        for (int i = 0; i < 4; i++) o[i] = vtile[c4 + i][n];
        *(u16x4*)(dst + (size_t)n * 1024 + c4) = o;
    }
}

// ---------------- fused differential attention + subln ----------------
// grid: 512 = B(2) * H(16) * (S/64=16) ; block 256 (4 waves, 16 q-rows each)
__global__ __launch_bounds__(256, 1) void k_attn(const unsigned short* __restrict__ QKV,
                                                 const unsigned short* __restrict__ Vt,
                                                 const float* __restrict__ mask,
                                                 const float* __restrict__ lamp,
                                                 const float* __restrict__ subln,
                                                 unsigned short* __restrict__ outc) {
    __shared__ unsigned short Ks[64 * 256];
    __shared__ unsigned short Vs[256 * 64];
    __shared__ unsigned short Ps1[4][16 * 64];
    __shared__ unsigned short Ps2[4][16 * 64];
    int blk = blockIdx.x;
    int qt = blk & 15, h = (blk >> 4) & 15, b = blk >> 8;
    int t = threadIdx.x, wave = t >> 6, lane = t & 63;
    int li = lane & 15, lg = lane >> 4;
    float lam = lamp[0];
    int q0 = qt * 64;

    // Q fragments (held in registers all kernel)
    const unsigned short* Qb = QKV + (size_t)(b * 1024 + q0 + wave * 16 + li) * 12288 + h * 256;
    bf16x8 qf1[4], qf2[4];
#pragma unroll
    for (int ks = 0; ks < 4; ks++) {
        qf1[ks] = *(const bf16x8*)(Qb + ks * 32 + lg * 8);
        qf2[ks] = *(const bf16x8*)(Qb + 128 + ks * 32 + lg * 8);
    }

    float m1[4], l1[4], m2[4], l2[4];
    f32x4 o1[16], o2[16];
#pragma unroll
    for (int r = 0; r < 4; r++) { m1[r] = -1e30f; m2[r] = -1e30f; l1[r] = 0.f; l2[r] = 0.f; }
#pragma unroll
    for (int n = 0; n < 16; n++)
#pragma unroll
        for (int r = 0; r < 4; r++) { o1[n][r] = 0.f; o2[n][r] = 0.f; }

    const float scale = 0.08838834764831845f;  // 1/sqrt(128)
    const float* mbase = mask + ((size_t)((b * 16 + h) * 1024 + q0 + wave * 16)) * 1024;
    const unsigned short* Kg0 = QKV + (size_t)(b * 1024) * 12288 + 4096 + h * 256;
    const unsigned short* Vg0 = Vt + (size_t)(b * 16 + h) * 256 * 1024;

    for (int kt = 0; kt < 16; kt++) {
        int t0 = kt * 64;
#pragma unroll
        for (int i = 0; i < 8; i++)
            gload16(Kg0 + (size_t)(t0 + i * 8 + (t >> 5)) * 12288 + (t & 31) * 8,
                    Ks + (i * 256 + t) * 8);
#pragma unroll
        for (int i = 0; i < 8; i++)
            gload16(Vg0 + (size_t)(i * 32 + (t >> 3)) * 1024 + t0 + (t & 7) * 8,
                    Vs + (i * 256 + t) * 8);
        __syncthreads();

        // QK^T (both components)
        f32x4 s1[4], s2[4];
#pragma unroll
        for (int n = 0; n < 4; n++)
#pragma unroll
            for (int r = 0; r < 4; r++) { s1[n][r] = 0.f; s2[n][r] = 0.f; }
#pragma unroll
        for (int n = 0; n < 4; n++) {
#pragma unroll
            for (int ks = 0; ks < 4; ks++) {
                bf16x8 kf1 = *(const bf16x8*)(Ks + (n * 16 + li) * 256 + ks * 32 + lg * 8);
                bf16x8 kf2 = *(const bf16x8*)(Ks + (n * 16 + li) * 256 + 128 + ks * 32 + lg * 8);
                s1[n] = mfma16(qf1[ks], kf1, s1[n]);
                s2[n] = mfma16(qf2[ks], kf2, s2[n]);
            }
        }
        // scale + mask
#pragma unroll
        for (int n = 0; n < 4; n++)
#pragma unroll
            for (int r = 0; r < 4; r++) {
                float mv = mbase[(size_t)(lg * 4 + r) * 1024 + t0 + n * 16 + li];
                s1[n][r] = s1[n][r] * scale + mv;
                s2[n][r] = s2[n][r] * scale + mv;
            }
        // per-row max (row = lg*4+r ; 16 lanes of group lg hold the 64 cols)
        float pm1[4], pm2[4];
#pragma unroll
        for (int r = 0; r < 4; r++) {
            pm1[r] = fmaxf(fmaxf(s1[0][r], s1[1][r]), fmaxf(s1[2][r], s1[3][r]));
            pm2[r] = fmaxf(fmaxf(s2[0][r], s2[1][r]), fmaxf(s2[2][r], s2[3][r]));
        }
#pragma unroll
        for (int off = 8; off; off >>= 1)
#pragma unroll
            for (int r = 0; r < 4; r++) {
                pm1[r] = fmaxf(pm1[r], __shfl_xor(pm1[r], off));
                pm2[r] = fmaxf(pm2[r], __shfl_xor(pm2[r], off));
            }
        // online-softmax merge
        float c1[4], c2[4];
#pragma unroll
        for (int r = 0; r < 4; r++) {
            float mn1 = fmaxf(m1[r], pm1[r]); c1[r] = __expf(m1[r] - mn1); m1[r] = mn1;
            float mn2 = fmaxf(m2[r], pm2[r]); c2[r] = __expf(m2[r] - mn2); m2[r] = mn2;
        }
        float rs1[4] = {0, 0, 0, 0}, rs2[4] = {0, 0, 0, 0};
#pragma unroll
        for (int n = 0; n < 4; n++)
#pragma unroll
            for (int r = 0; r < 4; r++) {
                float p1 = __expf(s1[n][r] - m1[r]); s1[n][r] = p1; rs1[r] += p1;
                float p2 = __expf(s2[n][r] - m2[r]); s2[n][r] = p2; rs2[r] += p2;
            }
#pragma unroll
        for (int off = 8; off; off >>= 1)
#pragma unroll
            for (int r = 0; r < 4; r++) {
                rs1[r] += __shfl_xor(rs1[r], off);
                rs2[r] += __shfl_xor(rs2[r], off);
            }
#pragma unroll
        for (int r = 0; r < 4; r++) {
            l1[r] = l1[r] * c1[r] + rs1[r];
            l2[r] = l2[r] * c2[r] + rs2[r];
        }
#pragma unroll
        for (int n = 0; n < 16; n++)
#pragma unroll
            for (int r = 0; r < 4; r++) { o1[n][r] *= c1[r]; o2[n][r] *= c2[r]; }
        // P -> LDS (transpose to A-fragment layout), wave-private regions
#pragma unroll
        for (int n = 0; n < 4; n++)
#pragma unroll
            for (int r = 0; r < 4; r++) {
                Ps1[wave][(lg * 4 + r) * 64 + n * 16 + li] = f2bf(s1[n][r]);
                Ps2[wave][(lg * 4 + r) * 64 + n * 16 + li] = f2bf(s2[n][r]);
            }
        // PV
#pragma unroll
        for (int ks = 0; ks < 2; ks++) {
            bf16x8 pa1 = *(const bf16x8*)(&Ps1[wave][li * 64 + ks * 32 + lg * 8]);
            bf16x8 pa2 = *(const bf16x8*)(&Ps2[wave][li * 64 + ks * 32 + lg * 8]);
#pragma unroll
            for (int n = 0; n < 16; n++) {
                bf16x8 vf = *(const bf16x8*)(Vs + (n * 16 + li) * 64 + ks * 32 + lg * 8);
                o1[n] = mfma16(pa1, vf, o1[n]);
                o2[n] = mfma16(pa2, vf, o2[n]);
            }
        }
        __syncthreads();
    }
    // epilogue: combine, subln rmsnorm (over 256), *0.2, store bf16
    float inv1[4], inv2[4];
#pragma unroll
    for (int r = 0; r < 4; r++) { inv1[r] = 1.f / l1[r]; inv2[r] = lam / l2[r]; }
    float ss[4] = {0, 0, 0, 0};
#pragma unroll
    for (int n = 0; n < 16; n++)
#pragma unroll
        for (int r = 0; r < 4; r++) {
            float v = o1[n][r] * inv1[r] - o2[n][r] * inv2[r];
            o1[n][r] = v;
            ss[r] += v * v;
        }
#pragma unroll
    for (int off = 8; off; off >>= 1)
#pragma unroll
        for (int r = 0; r < 4; r++) ss[r] += __shfl_xor(ss[r], off);
    float rn[4];
#pragma unroll
    for (int r = 0; r < 4; r++) rn[r] = rsqrtf(ss[r] * (1.f / 256.f) + 1e-6f);
#pragma unroll
    for (int n = 0; n < 16; n++) {
        float sw = subln[n * 16 + li];
#pragma unroll
        for (int r = 0; r < 4; r++) {
            outc[(size_t)(b * 1024 + q0 + wave * 16 + lg * 4 + r) * 4096 + h * 256 + n * 16 + li] =
                f2bf(o1[n][r] * rn[r] * sw * 0.2f);
        }
    }
}

// ---------------- rmsnorm over rows of 2048 ----------------
template <int WB>
__global__ __launch_bounds__(256) void k_rmsnorm(const float* __restrict__ in,
                                                 const float* __restrict__ w,
                                                 float* __restrict__ of,
                                                 unsigned short* __restrict__ ob) {
    int row = blockIdx.x, t = threadIdx.x;
    const float* x = in + (size_t)row * 2048;
    f32x4 a = ((const f32x4*)x)[t * 2];
    f32x4 b = ((const f32x4*)x)[t * 2 + 1];
    float s = 0.f;
#pragma unroll
    for (int i = 0; i < 4; i++) s += a[i] * a[i] + b[i] * b[i];
#pragma unroll
    for (int off = 32; off; off >>= 1) s += __shfl_xor(s, off);
    __shared__ float red[4];
    if ((t & 63) == 0) red[t >> 6] = s;
    __syncthreads();
    float tot = red[0] + red[1] + red[2] + red[3];
    float rn = rsqrtf(tot * (1.f / 2048.f) + 1e-6f);
    f32x4 wa = ((const f32x4*)w)[t * 2];
    f32x4 wb = ((const f32x4*)w)[t * 2 + 1];
    float* po = of + (size_t)row * 2048 + t * 8;
    unsigned short* pb = WB ? (ob + (size_t)row * 2048 + t * 8) : nullptr;
#pragma unroll
    for (int i = 0; i < 4; i++) {
        float y0 = a[i] * rn * wa[i];
        float y1 = b[i] * rn * wb[i];
        po[i] = y0; po[4 + i] = y1;
        if constexpr (WB) { pb[i] = f2bf(y0); pb[4 + i] = f2bf(y1); }
    }
}

// ---------------- swiglu: H[2048][8192] -> G bf16 [2048][4096] ----------------
__global__ __launch_bounds__(256) void k_swiglu(const float* __restrict__ H,
                                                unsigned short* __restrict__ G) {
    int idx = blockIdx.x * 256 + threadIdx.x;  // 4 elems each
    int row = idx >> 10, col4 = (idx & 1023) * 4;
    f32x4 a = *(const f32x4*)(H + (size_t)row * 8192 + col4);
    f32x4 c = *(const f32x4*)(H + (size_t)row * 8192 + 4096 + col4);
    u16x4 o;
#pragma unroll
    for (int i = 0; i < 4; i++) {
        float xv = a[i];
        float g = xv / (1.f + __expf(-xv)) * c[i];
        o[i] = f2bf(g);
    }
    *(u16x4*)(G + (size_t)row * 4096 + col4) = o;
}

// ---------------- launch ----------------
extern "C" void kernel_launch(void* const* d_in, const int* in_sizes, int n_in,
                              void* d_out, int out_size, void* d_ws, size_t ws_size,
                              hipStream_t stream) {
    const float* x      = (const float*)d_in[0];
    const float* mask   = (const float*)d_in[1];
    const float* Wq     = (const float*)d_in[2];
    const float* Wk     = (const float*)d_in[3];
    const float* Wv     = (const float*)d_in[4];
    const float* Wo     = (const float*)d_in[5];
    const float* lq1    = (const float*)d_in[6];
    const float* lk1    = (const float*)d_in[7];
    const float* lq2    = (const float*)d_in[8];
    const float* lk2    = (const float*)d_in[9];
    const float* subln  = (const float*)d_in[10];
    const float* attnw  = (const float*)d_in[11];
    const float* ffw    = (const float*)d_in[12];
    const float* w1     = (const float*)d_in[13];
    const float* w3     = (const float*)d_in[14];
    const float* w2     = (const float*)d_in[15];
    float* out = (float*)d_out;

    char* ws = (char*)d_ws;
    size_t off = 0;
    auto alloc = [&](size_t bytes) { size_t o = off; off += (bytes + 255) & ~(size_t)255; return o; };

    unsigned short* WT_QKV = (unsigned short*)(ws + alloc(12288ull * 2048 * 2)); // 50.3MB
    unsigned short* WT_O   = (unsigned short*)(ws + alloc(2048ull * 4096 * 2));  // 16.8MB
    unsigned short* WT_13  = (unsigned short*)(ws + alloc(8192ull * 2048 * 2));  // 33.6MB
    unsigned short* WT_2   = (unsigned short*)(ws + alloc(2048ull * 4096 * 2));  // 16.8MB
    unsigned short* XB     = (unsigned short*)(ws + alloc(2048ull * 2048 * 2));  // 8.4MB
    size_t qkv_off = alloc(2048ull * 12288 * 2);                                  // 50.3MB
    unsigned short* QKV    = (unsigned short*)(ws + qkv_off);
    unsigned short* VT     = (unsigned short*)(ws + alloc(32ull * 256 * 1024 * 2)); // 16.8MB (contig after QKV)
    float*          Hbuf   = (float*)(ws + qkv_off);  // overlay QKV+VT (exactly 64MB) after attention
    size_t att_off = alloc(2048ull * 4096 * 2);                                   // 16.8MB
    unsigned short* ATT    = (unsigned short*)(ws + att_off);
    unsigned short* G      = (unsigned short*)(ws + att_off);  // overlay (ATT dead after Wo GEMM)
    size_t asum_off = alloc(2048ull * 2048 * 4);                                  // 16.8MB
    float*          ASUM   = (float*)(ws + asum_off);
    float*          FSUM   = (float*)(ws + asum_off);  // overlay (ASUM dead after rmsnorm)
    float*          ABLK32 = (float*)(ws + alloc(2048ull * 2048 * 4));            // 16.8MB
    unsigned short* ABLK16 = (unsigned short*)(ws + alloc(2048ull * 2048 * 2));   // 8.4MB
    float*          LAM    = (float*)(ws + alloc(256));

    // weight prep
    k_transpose_cast<<<dim3(64, 32), 256, 0, stream>>>(Wq, WT_QKV, 2048, 4096);
    k_transpose_cast<<<dim3(64, 32), 256, 0, stream>>>(Wk, WT_QKV + 4096ull * 2048, 2048, 4096);
    k_transpose_cast<<<dim3(64, 32), 256, 0, stream>>>(Wv, WT_QKV + 8192ull * 2048, 2048, 4096);
    k_transpose_cast<<<dim3(32, 64), 256, 0, stream>>>(Wo, WT_O, 4096, 2048);
    k_transpose_cast<<<dim3(64, 32), 256, 0, stream>>>(w1, WT_13, 2048, 4096);
    k_transpose_cast<<<dim3(64, 32), 256, 0, stream>>>(w3, WT_13 + 4096ull * 2048, 2048, 4096);
    k_transpose_cast<<<dim3(32, 64), 256, 0, stream>>>(w2, WT_2, 4096, 2048);
    k_cast_bf16<<<2048, 256, 0, stream>>>(x, XB, 524288);
    k_lam<<<1, 128, 0, stream>>>(lq1, lk1, lq2, lk2, LAM);

    // QKV projection
    k_gemm<0><<<dim3(16, 96), 256, 0, stream>>>(XB, WT_QKV, QKV, nullptr, 2048, 12288, 2048);
    k_vtrans<<<dim3(16, 4, 32), 256, 0, stream>>>(QKV, VT);
    // differential attention + subln
    k_attn<<<512, 256, 0, stream>>>(QKV, VT, mask, LAM, subln, ATT);
    // Wo projection + residual
    k_gemm<1><<<dim3(16, 16), 256, 0, stream>>>(ATT, WT_O, ASUM, x, 2048, 2048, 4096);
    k_rmsnorm<1><<<2048, 256, 0, stream>>>(ASUM, attnw, ABLK32, ABLK16);
    // FFN
    k_gemm<2><<<dim3(16, 64), 256, 0, stream>>>(ABLK16, WT_13, Hbuf, nullptr, 2048, 8192, 2048);
    k_swiglu<<<8192, 256, 0, stream>>>(Hbuf, G);
    k_gemm<1><<<dim3(16, 16), 256, 0, stream>>>(G, WT_2, FSUM, ABLK32, 2048, 2048, 4096);
    k_rmsnorm<0><<<2048, 256, 0, stream>>>(FSUM, ffw, out, nullptr);
}